// Round 3
// baseline (651.662 us; speedup 1.0000x reference)
//
#include <hip/hip_runtime.h>
#include <math.h>
#include <stdint.h>

typedef float f4u __attribute__((ext_vector_type(4), aligned(4)));
typedef unsigned int u4v __attribute__((ext_vector_type(4)));
typedef __attribute__((ext_vector_type(8))) short short8;   // 8 bf16 (4 VGPR)
typedef __attribute__((ext_vector_type(4))) float float4v;  // MFMA acc

#define DIM 256
#define KCB 1024
#define PERP_OFF 16777217
#define ENC_OFF  16777218
#define CAP 32
#define EPS 0.008f
#define NPB 128            // n per score block (was 256)
#define SCORE_BLOCKS 512   // 512 * 128 = 65536 n

// ---------------------------------------------------------------------------
// numpy pairwise sum-of-squares of a 128-block (8 accumulators, pairwise
// combine); squares rounded separately; no fma contraction.
// ---------------------------------------------------------------------------
__device__ __forceinline__ float np_sumsq128(const float* a, int stride) {
  float r[8];
  #pragma unroll
  for (int j = 0; j < 8; ++j) { float v = a[j * stride]; r[j] = __fmul_rn(v, v); }
  #pragma unroll
  for (int i = 8; i < 128; i += 8) {
    #pragma unroll
    for (int j = 0; j < 8; ++j) {
      float v = a[(i + j) * stride];
      r[j] = __fadd_rn(r[j], __fmul_rn(v, v));
    }
  }
  float s01 = __fadd_rn(r[0], r[1]);
  float s23 = __fadd_rn(r[2], r[3]);
  float s45 = __fadd_rn(r[4], r[5]);
  float s67 = __fadd_rn(r[6], r[7]);
  return __fadd_rn(__fadd_rn(s01, s23), __fadd_rn(s45, s67));
}

__device__ __forceinline__ unsigned short f2bf(float f) {
  unsigned u = __float_as_uint(f);
  u += 0x7FFFu + ((u >> 16) & 1u);     // RNE
  return (unsigned short)(u >> 16);
}

// ---------------------------------------------------------------------------
// k_prep: cb_t[d][k] (fp32, for k_epi gathers), e_bf16[k][d], np-exact
// cb_sq[k] (lane 0, row L1-hot), zero counts. grid 1024 x 64.
// ---------------------------------------------------------------------------
__global__ __launch_bounds__(64)
void k_prep(const float* __restrict__ cb, float* __restrict__ cb_t,
            unsigned short* __restrict__ e_bf16, float* __restrict__ cb_sq,
            int* __restrict__ counts) {
  const int k = blockIdx.x;
  const int l = threadIdx.x;                  // 0..63
  float4 v = ((const float4*)(cb + k * DIM))[l];
  cb_t[(l*4+0)*KCB + k] = v.x;
  cb_t[(l*4+1)*KCB + k] = v.y;
  cb_t[(l*4+2)*KCB + k] = v.z;
  cb_t[(l*4+3)*KCB + k] = v.w;
  unsigned short bs[4] = {f2bf(v.x), f2bf(v.y), f2bf(v.z), f2bf(v.w)};
  *(ushort4*)(e_bf16 + k * DIM + l * 4) = *(ushort4*)bs;
  if (l == 0) {
    const float* p = cb + k * DIM;
    cb_sq[k] = __fadd_rn(np_sumsq128(p, 1), np_sumsq128(p + 128, 1));
    counts[k] = 0;
  }
}

// ---------------------------------------------------------------------------
// k_score v4 (SINGLE-PASS, high-occupancy): bf16 MFMA approx scores
// s = cb_sq[k] - 2*dot. Online capture: per-ct cross-lane running min m;
// capture (idx, s) when s <= m + EPS (superset of the final set since m only
// decreases); end-of-kernel filter s <= m_final + EPS recovers EXACTLY the
// old two-pass candidate set -> bitwise-identical refine/output.
// v4 change: 512 score blocks x 128 n (wave owns 32 n, Bf[2][8] = 64 VGPR),
// LDS 25.6KB -> 3 blocks/CU = 12 waves/CU (was 1 block = 4 waves/CU): pure
// TLP increase for a latency-bound kernel (R2: Occ 5.6%, MfmaUtil 3.5%).
// Blocks 512..767: the old k_insq (np-exact in_sq), hidden under score time.
//   A-frag: e_bf16[(ct*16 + l15)*256 + ks*32 + quad*8] (16B contiguous)
//   B-frag: gathered once from fp32 x (NCHW), packed bf16, held in VGPRs.
//   D: col=lane&15 = vector, row=quad*4+reg = code.  (layout HW-verified R4)
// ---------------------------------------------------------------------------
__global__ __launch_bounds__(256, 3)
void k_score(const float* __restrict__ x, const unsigned short* __restrict__ e_bf16,
             const float* __restrict__ cb_sq, unsigned int* __restrict__ gcnt,
             unsigned short* __restrict__ glist, float* __restrict__ in_sq) {
  if (blockIdx.x >= SCORE_BLOCKS) {
    // ---- insq role: np-exact in_sq[n]; lanes = consecutive w, coalesced ----
    const int n = (blockIdx.x - SCORE_BLOCKS) * 256 + threadIdx.x;
    const int b = n >> 12;
    const int hw = n & 4095;
    const float* p = x + b * 1048576 + hw;
    float h0 = np_sumsq128(p, 4096);
    float h1 = np_sumsq128(p + 128 * 4096, 4096);
    in_sq[n] = __fadd_rn(h0, h1);
    return;
  }

  __shared__ unsigned int   lcnt[NPB];
  __shared__ unsigned short llist[NPB * CAP];   // 8KB
  __shared__ float          lsc[NPB * CAP];     // 16KB (captured approx scores)
  __shared__ float          lmin[NPB];          // per-n final min
  const int t    = threadIdx.x;
  const int wv   = t >> 6;
  const int lane = t & 63;
  const int l15  = lane & 15;
  const int quad = lane >> 4;
  if (t < NPB) lcnt[t] = 0;
  __syncthreads();

  // --- B-frag setup: 2 n-groups x 8 K-steps, gathered from fp32 x ---
  short8 Bf[2][8];
  const int nbase = blockIdx.x * NPB + wv * 32;
  #pragma unroll
  for (int g = 0; g < 2; ++g) {
    const int n = nbase + g * 16 + l15;
    const float* xb = x + (n >> 12) * 1048576 + (n & 4095);
    #pragma unroll
    for (int ks = 0; ks < 8; ++ks) {
      const int d0 = ks * 32 + quad * 8;
      union { unsigned short s[8]; short8 v; } u;
      #pragma unroll
      for (int j = 0; j < 8; ++j) u.s[j] = f2bf(xb[(d0 + j) * 4096]);
      Bf[g][ks] = u.v;
    }
  }

  // ---- single pass: MFMA + online min + online capture ----
  float m[2] = {1e30f, 1e30f};
  for (int ct = 0; ct < 64; ++ct) {
    float4v acc[2];
    #pragma unroll
    for (int g = 0; g < 2; ++g) acc[g] = (float4v){0.f, 0.f, 0.f, 0.f};
    const unsigned short* ap = e_bf16 + (ct * 16 + l15) * DIM + quad * 8;
    #pragma unroll
    for (int ks = 0; ks < 8; ++ks) {
      const short8 a = *(const short8*)(ap + ks * 32);
      #pragma unroll
      for (int g = 0; g < 2; ++g)
        acc[g] = __builtin_amdgcn_mfma_f32_16x16x32_bf16(a, Bf[g][ks], acc[g], 0, 0, 0);
    }
    const float4 cs = *(const float4*)(cb_sq + ct * 16 + quad * 4);
    #pragma unroll
    for (int g = 0; g < 2; ++g) {
      const float sa[4] = {fmaf(-2.f, acc[g].x, cs.x), fmaf(-2.f, acc[g].y, cs.y),
                           fmaf(-2.f, acc[g].z, cs.z), fmaf(-2.f, acc[g].w, cs.w)};
      // running cross-lane min for this n (fmin is exact -> order-independent)
      float bm = fminf(fminf(sa[0], sa[1]), fminf(sa[2], sa[3]));
      bm = fminf(bm, m[g]);
      bm = fminf(bm, __shfl_xor(bm, 16));
      bm = fminf(bm, __shfl_xor(bm, 32));
      m[g] = bm;
      const float thr = bm + EPS;
      const float sblk = fminf(fminf(sa[0], sa[1]), fminf(sa[2], sa[3]));
      if (sblk <= thr) {               // rare: skip whole capture block
        const int nl = wv * 32 + g * 16 + l15;
        #pragma unroll
        for (int r = 0; r < 4; ++r) {
          if (sa[r] <= thr) {
            unsigned slot = atomicAdd(&lcnt[nl], 1u);
            if (slot < CAP) {
              llist[nl * CAP + slot] = (unsigned short)(ct * 16 + quad * 4 + r);
              lsc[nl * CAP + slot]   = sa[r];
            }
          }
        }
      }
    }
  }
  // publish per-n final min (same value across quads after shfl reduction)
  if (quad == 0) {
    #pragma unroll
    for (int g = 0; g < 2; ++g) lmin[wv * 32 + g * 16 + l15] = m[g];
  }
  __syncthreads();

  // ---- filter to EXACT two-pass set: s <= m_final + EPS; compact in place,
  // then dump own row (no extra barrier: filter & dump same thread) ----
  if (t < NPB) {
    const unsigned cnt = lcnt[t];
    unsigned outc = cnt;
    if (cnt <= CAP) {
      const float thrf = lmin[t] + EPS;
      unsigned j = 0;
      for (unsigned i = 0; i < cnt; ++i) {
        const unsigned short c = llist[t * CAP + i];
        if (lsc[t * CAP + i] <= thrf) llist[t * CAP + j++] = c;
      }
      outc = j;
    }
    gcnt[blockIdx.x * NPB + t] = outc;

    // dump own row: CAP*2B = 64B = 4 x 16B
    u4v* gdst = (u4v*)(glist + (size_t)blockIdx.x * NPB * CAP);
    const u4v* lsrc = (const u4v*)llist;
    #pragma unroll
    for (int j = 0; j < 4; ++j)
      __builtin_nontemporal_store(lsrc[t * 4 + j], gdst + t * 4 + j);
  }
}

// ---------------------------------------------------------------------------
// k_refine: np-exact fp32 dist (bitwise = R3's chain) over captured
// candidates; 2 threads per n, dual chains share x loads; coalesced x reads.
// grid 512 x 256.
// ---------------------------------------------------------------------------
__global__ __launch_bounds__(256)
void k_refine(const float* __restrict__ x, const float* __restrict__ cb,
              const float* __restrict__ cb_sq, const float* __restrict__ in_sq,
              const unsigned int* __restrict__ gcnt,
              const unsigned short* __restrict__ glist,
              int* __restrict__ best_idx) {
  const int tid  = blockIdx.x * 256 + threadIdx.x;
  const int n    = tid >> 1;
  const int half = tid & 1;
  const unsigned cnt = gcnt[n];
  const float* xb = x + (n >> 12) * 1048576 + (n & 4095);
  const float isq = in_sq[n];
  float bv = 1e30f; int bc = 0x7FFFFFFF;

  if (cnt <= CAP) {
    const unsigned short* lst = glist + (size_t)n * CAP;
    for (unsigned i = half; i < cnt; i += 4) {
      const int c1 = lst[i];
      const bool has2 = (i + 2) < cnt;
      const int c2 = has2 ? lst[i + 2] : c1;
      const float* e1 = cb + c1 * DIM;
      const float* e2 = cb + c2 * DIM;
      float d1 = 0.f, d2 = 0.f;
      #pragma unroll 8
      for (int d = 0; d < DIM; ++d) {
        const float xv = xb[d * 4096];
        d1 = fmaf(xv, e1[d], d1);
        d2 = fmaf(xv, e2[d], d2);
      }
      {
        const float dist = __fsub_rn(__fadd_rn(isq, cb_sq[c1]), __fmul_rn(2.f, d1));
        if (dist < bv || (dist == bv && c1 < bc)) { bv = dist; bc = c1; }
      }
      if (has2) {
        const float dist = __fsub_rn(__fadd_rn(isq, cb_sq[c2]), __fmul_rn(2.f, d2));
        if (dist < bv || (dist == bv && c2 < bc)) { bv = dist; bc = c2; }
      }
    }
  } else {
    // overflow fallback (P ~ 1e-9 over the whole problem): exact full scan
    for (int c = half; c < KCB; c += 2) {
      const float* e1 = cb + c * DIM;
      float d1 = 0.f;
      #pragma unroll 8
      for (int d = 0; d < DIM; ++d) d1 = fmaf(xb[d * 4096], e1[d], d1);
      const float dist = __fsub_rn(__fadd_rn(isq, cb_sq[c]), __fmul_rn(2.f, d1));
      if (dist < bv || (dist == bv && c < bc)) { bv = dist; bc = c; }
    }
  }
  const float ov = __shfl_xor(bv, 1);
  const int   oc = __shfl_xor(bc, 1);
  if (ov < bv || (ov == bv && oc < bc)) { bv = ov; bc = oc; }
  if (half == 0) best_idx[n] = bc;
}

// ---------------------------------------------------------------------------
// k_epi: fused epilogue (one block per (b,h)): one-hot encodings (coalesced,
// nontemporal), histogram, xq straight-through + double loss partial.
// grid 1024 x 256.
// ---------------------------------------------------------------------------
__global__ __launch_bounds__(256)
void k_epi(const float* __restrict__ x, const float* __restrict__ cb_t,
           const int* __restrict__ best_idx, float* __restrict__ out1,
           float* __restrict__ enc, int* __restrict__ counts,
           double* __restrict__ partials) {
  const int t  = threadIdx.x;
  const int bh = blockIdx.x;
  const int b  = bh >> 6, h = bh & 63;
  __shared__ int idxs[64];
  if (t < 64) {
    const int myidx = best_idx[bh * 64 + t];
    idxs[t] = myidx;
    atomicAdd(counts + myidx, 1);
  }
  __syncthreads();

  {
    float* base = enc + (size_t)bh * 65536 + t * 4;
    #pragma unroll 8
    for (int r = 0; r < 64; ++r) {
      const int bi = idxs[r];
      f4u v = {0.f, 0.f, 0.f, 0.f};
      if ((bi >> 2) == t) {
        if ((bi & 3) == 0) v.x = 1.f; else if ((bi & 3) == 1) v.y = 1.f;
        else if ((bi & 3) == 2) v.z = 1.f; else v.w = 1.f;
      }
      __builtin_nontemporal_store(v, (f4u*)(base + r * 1024));
    }
  }

  const int w4 = (t & 15) * 4;
  const int cg = t >> 4;
  const int i0 = idxs[w4], i1 = idxs[w4+1], i2 = idxs[w4+2], i3 = idxs[w4+3];
  double s = 0.0;
  #pragma unroll 4
  for (int j = 0; j < 16; ++j) {
    const int c = cg * 16 + j;
    const size_t off = ((size_t)b << 20) + ((size_t)c << 12) + (h << 6) + w4;
    const float4 xp = *(const float4*)(x + off);
    const float* row = cb_t + c * KCB;
    const float q0 = row[i0], q1 = row[i1], q2 = row[i2], q3 = row[i3];
    const float d0 = __fsub_rn(q0, xp.x), d1 = __fsub_rn(q1, xp.y);
    const float d2 = __fsub_rn(q2, xp.z), d3 = __fsub_rn(q3, xp.w);
    f4u o;
    o.x = __fadd_rn(xp.x, d0); o.y = __fadd_rn(xp.y, d1);
    o.z = __fadd_rn(xp.z, d2); o.w = __fadd_rn(xp.w, d3);
    __builtin_nontemporal_store(o, (f4u*)(out1 + off));
    s += (double)(d0*d0) + (double)(d1*d1) + (double)(d2*d2) + (double)(d3*d3);
  }
  #pragma unroll
  for (int off = 32; off > 0; off >>= 1) s += __shfl_down(s, off);
  __shared__ double sm[4];
  if ((t & 63) == 0) sm[t >> 6] = s;
  __syncthreads();
  if (t == 0) partials[bh] = (sm[0] + sm[1]) + (sm[2] + sm[3]);
}

// ---------------------------------------------------------------------------
// k_final: loss + perplexity. grid 1 x 256
// ---------------------------------------------------------------------------
__global__ __launch_bounds__(256)
void k_final(const double* __restrict__ partials, const int* __restrict__ counts,
             float* __restrict__ out) {
  const int t = threadIdx.x;
  double s = 0.0;
  #pragma unroll
  for (int i = 0; i < 4; ++i) s += partials[t + i * 256];
  #pragma unroll
  for (int off = 32; off > 0; off >>= 1) s += __shfl_down(s, off);
  __shared__ double sm[4];
  __shared__ float smf[4];
  if ((t & 63) == 0) sm[t >> 6] = s;

  float ps = 0.f;
  #pragma unroll
  for (int i = 0; i < 4; ++i) {
    const float p = (float)counts[t + i * 256] * (1.0f / 65536.0f);
    ps += p * logf(1.0e10f + p);
  }
  #pragma unroll
  for (int off = 32; off > 0; off >>= 1) ps += __shfl_down(ps, off);
  if ((t & 63) == 0) smf[t >> 6] = ps;
  __syncthreads();
  if (t == 0) {
    const double tot = (sm[0] + sm[1]) + (sm[2] + sm[3]);
    const float mval = (float)(tot / 16777216.0);
    out[0] = mval + 0.25f * mval;
    out[PERP_OFF] = expf(-((smf[0] + smf[1]) + (smf[2] + smf[3])));
  }
}

// ---------------------------------------------------------------------------
extern "C" void kernel_launch(void* const* d_in, const int* in_sizes, int n_in,
                              void* d_out, int out_size, void* d_ws, size_t ws_size,
                              hipStream_t stream) {
  const float* x  = (const float*)d_in[0];   // (16,256,64,64) fp32
  const float* cb = (const float*)d_in[1];   // (1024,256) fp32
  float* out = (float*)d_out;
  char*  ws  = (char*)d_ws;

  int*            counts   = (int*)(ws + 0);                //   4 KB
  float*          cb_sq    = (float*)(ws + 4096);           //   4 KB
  int*            best_idx = (int*)(ws + 8192);             // 256 KB
  float*          in_sq    = (float*)(ws + 270336);         // 256 KB
  double*         partials = (double*)(ws + 532480);        //   8 KB
  float*          cb_t     = (float*)(ws + 540672);         //   1 MB
  unsigned short* e_bf16   = (unsigned short*)(ws + 1589248); // 512 KB
  unsigned int*   gcnt     = (unsigned int*)(ws + 2113536); // 256 KB
  unsigned short* glist    = (unsigned short*)(ws + 2375680); // 4 MB

  k_prep  <<<1024, 64, 0, stream>>>(cb, cb_t, e_bf16, cb_sq, counts);
  k_score <<<SCORE_BLOCKS + 256, 256, 0, stream>>>(x, e_bf16, cb_sq, gcnt, glist, in_sq);
  k_refine<<<512, 256, 0, stream>>>(x, cb, cb_sq, in_sq, gcnt, glist, best_idx);
  k_epi   <<<1024, 256, 0, stream>>>(x, cb_t, best_idx, out + 1,
                                     out + ENC_OFF, counts, partials);
  k_final <<<1, 256, 0, stream>>>(partials, counts, out);
}

// Round 4
// 638.542 us; speedup vs baseline: 1.0205x; 1.0205x over previous
//
#include <hip/hip_runtime.h>
#include <math.h>
#include <stdint.h>

typedef float f4u __attribute__((ext_vector_type(4), aligned(4)));
typedef unsigned int u4v __attribute__((ext_vector_type(4)));
typedef __attribute__((ext_vector_type(8))) short short8;   // 8 bf16 (4 VGPR)
typedef __attribute__((ext_vector_type(4))) float float4v;  // MFMA acc

#define DIM 256
#define KCB 1024
#define PERP_OFF 16777217
#define ENC_OFF  16777218
#define CAP 32
#define EPS 0.008f
#define NPB 128            // n per score block
#define SCORE_BLOCKS 512   // 512 * 128 = 65536 n

// ---------------------------------------------------------------------------
// numpy pairwise sum-of-squares of a 128-block (8 accumulators, pairwise
// combine); squares rounded separately; no fma contraction.
// ---------------------------------------------------------------------------
__device__ __forceinline__ float np_sumsq128(const float* a, int stride) {
  float r[8];
  #pragma unroll
  for (int j = 0; j < 8; ++j) { float v = a[j * stride]; r[j] = __fmul_rn(v, v); }
  #pragma unroll
  for (int i = 8; i < 128; i += 8) {
    #pragma unroll
    for (int j = 0; j < 8; ++j) {
      float v = a[(i + j) * stride];
      r[j] = __fadd_rn(r[j], __fmul_rn(v, v));
    }
  }
  float s01 = __fadd_rn(r[0], r[1]);
  float s23 = __fadd_rn(r[2], r[3]);
  float s45 = __fadd_rn(r[4], r[5]);
  float s67 = __fadd_rn(r[6], r[7]);
  return __fadd_rn(__fadd_rn(s01, s23), __fadd_rn(s45, s67));
}

__device__ __forceinline__ unsigned short f2bf(float f) {
  unsigned u = __float_as_uint(f);
  u += 0x7FFFu + ((u >> 16) & 1u);     // RNE
  return (unsigned short)(u >> 16);
}

// ---------------------------------------------------------------------------
// k_prep v2: e_bf16[k][d], np-exact cb_sq[k], zero counts. cb_t DROPPED
// (k_epi now reads original cb directly). grid 1024 x 64.
// ---------------------------------------------------------------------------
__global__ __launch_bounds__(64)
void k_prep(const float* __restrict__ cb, unsigned short* __restrict__ e_bf16,
            float* __restrict__ cb_sq, int* __restrict__ counts) {
  const int k = blockIdx.x;
  const int l = threadIdx.x;                  // 0..63
  float4 v = ((const float4*)(cb + k * DIM))[l];
  unsigned short bs[4] = {f2bf(v.x), f2bf(v.y), f2bf(v.z), f2bf(v.w)};
  *(ushort4*)(e_bf16 + k * DIM + l * 4) = *(ushort4*)bs;
  if (l == 0) {
    const float* p = cb + k * DIM;
    cb_sq[k] = __fadd_rn(np_sumsq128(p, 1), np_sumsq128(p + 128, 1));
    counts[k] = 0;
  }
}

// ---------------------------------------------------------------------------
// k_score v4 (SINGLE-PASS, high-occupancy): unchanged from R3.
// Online capture with running cross-lane min; end filter recovers the exact
// two-pass candidate set; overflow -> exact full-scan fallback in refine.
// Blocks 512..767: the old k_insq (np-exact in_sq).
// ---------------------------------------------------------------------------
__global__ __launch_bounds__(256, 3)
void k_score(const float* __restrict__ x, const unsigned short* __restrict__ e_bf16,
             const float* __restrict__ cb_sq, unsigned int* __restrict__ gcnt,
             unsigned short* __restrict__ glist, float* __restrict__ in_sq) {
  if (blockIdx.x >= SCORE_BLOCKS) {
    // ---- insq role: np-exact in_sq[n]; lanes = consecutive w, coalesced ----
    const int n = (blockIdx.x - SCORE_BLOCKS) * 256 + threadIdx.x;
    const int b = n >> 12;
    const int hw = n & 4095;
    const float* p = x + b * 1048576 + hw;
    float h0 = np_sumsq128(p, 4096);
    float h1 = np_sumsq128(p + 128 * 4096, 4096);
    in_sq[n] = __fadd_rn(h0, h1);
    return;
  }

  __shared__ unsigned int   lcnt[NPB];
  __shared__ unsigned short llist[NPB * CAP];   // 8KB
  __shared__ float          lsc[NPB * CAP];     // 16KB (captured approx scores)
  __shared__ float          lmin[NPB];          // per-n final min
  const int t    = threadIdx.x;
  const int wv   = t >> 6;
  const int lane = t & 63;
  const int l15  = lane & 15;
  const int quad = lane >> 4;
  if (t < NPB) lcnt[t] = 0;
  __syncthreads();

  // --- B-frag setup: 2 n-groups x 8 K-steps, gathered from fp32 x ---
  short8 Bf[2][8];
  const int nbase = blockIdx.x * NPB + wv * 32;
  #pragma unroll
  for (int g = 0; g < 2; ++g) {
    const int n = nbase + g * 16 + l15;
    const float* xb = x + (n >> 12) * 1048576 + (n & 4095);
    #pragma unroll
    for (int ks = 0; ks < 8; ++ks) {
      const int d0 = ks * 32 + quad * 8;
      union { unsigned short s[8]; short8 v; } u;
      #pragma unroll
      for (int j = 0; j < 8; ++j) u.s[j] = f2bf(xb[(d0 + j) * 4096]);
      Bf[g][ks] = u.v;
    }
  }

  // ---- single pass: MFMA + online min + online capture ----
  float m[2] = {1e30f, 1e30f};
  for (int ct = 0; ct < 64; ++ct) {
    float4v acc[2];
    #pragma unroll
    for (int g = 0; g < 2; ++g) acc[g] = (float4v){0.f, 0.f, 0.f, 0.f};
    const unsigned short* ap = e_bf16 + (ct * 16 + l15) * DIM + quad * 8;
    #pragma unroll
    for (int ks = 0; ks < 8; ++ks) {
      const short8 a = *(const short8*)(ap + ks * 32);
      #pragma unroll
      for (int g = 0; g < 2; ++g)
        acc[g] = __builtin_amdgcn_mfma_f32_16x16x32_bf16(a, Bf[g][ks], acc[g], 0, 0, 0);
    }
    const float4 cs = *(const float4*)(cb_sq + ct * 16 + quad * 4);
    #pragma unroll
    for (int g = 0; g < 2; ++g) {
      const float sa[4] = {fmaf(-2.f, acc[g].x, cs.x), fmaf(-2.f, acc[g].y, cs.y),
                           fmaf(-2.f, acc[g].z, cs.z), fmaf(-2.f, acc[g].w, cs.w)};
      // running cross-lane min for this n (fmin is exact -> order-independent)
      float bm = fminf(fminf(sa[0], sa[1]), fminf(sa[2], sa[3]));
      bm = fminf(bm, m[g]);
      bm = fminf(bm, __shfl_xor(bm, 16));
      bm = fminf(bm, __shfl_xor(bm, 32));
      m[g] = bm;
      const float thr = bm + EPS;
      const float sblk = fminf(fminf(sa[0], sa[1]), fminf(sa[2], sa[3]));
      if (sblk <= thr) {               // rare: skip whole capture block
        const int nl = wv * 32 + g * 16 + l15;
        #pragma unroll
        for (int r = 0; r < 4; ++r) {
          if (sa[r] <= thr) {
            unsigned slot = atomicAdd(&lcnt[nl], 1u);
            if (slot < CAP) {
              llist[nl * CAP + slot] = (unsigned short)(ct * 16 + quad * 4 + r);
              lsc[nl * CAP + slot]   = sa[r];
            }
          }
        }
      }
    }
  }
  // publish per-n final min (same value across quads after shfl reduction)
  if (quad == 0) {
    #pragma unroll
    for (int g = 0; g < 2; ++g) lmin[wv * 32 + g * 16 + l15] = m[g];
  }
  __syncthreads();

  // ---- filter to EXACT two-pass set: s <= m_final + EPS; compact in place,
  // then dump own row (no extra barrier: filter & dump same thread) ----
  if (t < NPB) {
    const unsigned cnt = lcnt[t];
    unsigned outc = cnt;
    if (cnt <= CAP) {
      const float thrf = lmin[t] + EPS;
      unsigned j = 0;
      for (unsigned i = 0; i < cnt; ++i) {
        const unsigned short c = llist[t * CAP + i];
        if (lsc[t * CAP + i] <= thrf) llist[t * CAP + j++] = c;
      }
      outc = j;
    }
    gcnt[blockIdx.x * NPB + t] = outc;

    // dump own row: CAP*2B = 64B = 4 x 16B
    u4v* gdst = (u4v*)(glist + (size_t)blockIdx.x * NPB * CAP);
    const u4v* lsrc = (const u4v*)llist;
    #pragma unroll
    for (int j = 0; j < 4; ++j)
      __builtin_nontemporal_store(lsrc[t * 4 + j], gdst + t * 4 + j);
  }
}

// ---------------------------------------------------------------------------
// k_refine v2: np-exact fp32 dist (bitwise = R3's chain) over captured
// candidates; 2 threads per n, dual chains share x loads; cb rows now read
// as float4 (contiguous rows -> 4x fewer gather instrs, 64B-efficient lines);
// fmaf chain order per accumulator unchanged. grid 512 x 256.
// ---------------------------------------------------------------------------
__global__ __launch_bounds__(256)
void k_refine(const float* __restrict__ x, const float* __restrict__ cb,
              const float* __restrict__ cb_sq, const float* __restrict__ in_sq,
              const unsigned int* __restrict__ gcnt,
              const unsigned short* __restrict__ glist,
              int* __restrict__ best_idx) {
  const int tid  = blockIdx.x * 256 + threadIdx.x;
  const int n    = tid >> 1;
  const int half = tid & 1;
  const unsigned cnt = gcnt[n];
  const float* xb = x + (n >> 12) * 1048576 + (n & 4095);
  const float isq = in_sq[n];
  float bv = 1e30f; int bc = 0x7FFFFFFF;

  if (cnt <= CAP) {
    const unsigned short* lst = glist + (size_t)n * CAP;
    for (unsigned i = half; i < cnt; i += 4) {
      const int c1 = lst[i];
      const bool has2 = (i + 2) < cnt;
      const int c2 = has2 ? lst[i + 2] : c1;
      const float4* e1 = (const float4*)(cb + c1 * DIM);
      const float4* e2 = (const float4*)(cb + c2 * DIM);
      float d1 = 0.f, d2 = 0.f;
      #pragma unroll 4
      for (int q = 0; q < 64; ++q) {
        const float4 a  = e1[q];
        const float4 bq = e2[q];
        const float x0 = xb[(q * 4 + 0) * 4096];
        const float x1 = xb[(q * 4 + 1) * 4096];
        const float x2 = xb[(q * 4 + 2) * 4096];
        const float x3 = xb[(q * 4 + 3) * 4096];
        d1 = fmaf(x0, a.x, d1);   d2 = fmaf(x0, bq.x, d2);
        d1 = fmaf(x1, a.y, d1);   d2 = fmaf(x1, bq.y, d2);
        d1 = fmaf(x2, a.z, d1);   d2 = fmaf(x2, bq.z, d2);
        d1 = fmaf(x3, a.w, d1);   d2 = fmaf(x3, bq.w, d2);
      }
      {
        const float dist = __fsub_rn(__fadd_rn(isq, cb_sq[c1]), __fmul_rn(2.f, d1));
        if (dist < bv || (dist == bv && c1 < bc)) { bv = dist; bc = c1; }
      }
      if (has2) {
        const float dist = __fsub_rn(__fadd_rn(isq, cb_sq[c2]), __fmul_rn(2.f, d2));
        if (dist < bv || (dist == bv && c2 < bc)) { bv = dist; bc = c2; }
      }
    }
  } else {
    // overflow fallback (P ~ 1e-9 over the whole problem): exact full scan
    for (int c = half; c < KCB; c += 2) {
      const float4* e1 = (const float4*)(cb + c * DIM);
      float d1 = 0.f;
      #pragma unroll 4
      for (int q = 0; q < 64; ++q) {
        const float4 a = e1[q];
        d1 = fmaf(xb[(q * 4 + 0) * 4096], a.x, d1);
        d1 = fmaf(xb[(q * 4 + 1) * 4096], a.y, d1);
        d1 = fmaf(xb[(q * 4 + 2) * 4096], a.z, d1);
        d1 = fmaf(xb[(q * 4 + 3) * 4096], a.w, d1);
      }
      const float dist = __fsub_rn(__fadd_rn(isq, cb_sq[c]), __fmul_rn(2.f, d1));
      if (dist < bv || (dist == bv && c < bc)) { bv = dist; bc = c; }
    }
  }
  const float ov = __shfl_xor(bv, 1);
  const int   oc = __shfl_xor(bc, 1);
  if (ov < bv || (ov == bv && oc < bc)) { bv = ov; bc = oc; }
  if (half == 0) best_idx[n] = bc;
}

// ---------------------------------------------------------------------------
// k_epi v2: fused epilogue (one block per (b,h)). Reads codebook rows
// DIRECTLY from cb via float4 preload (16 vec loads/thread replacing 64
// scalar cb_t gathers; lanes sharing a row read consecutive 64B segments).
// One-hot enc + histogram + xq straight-through + double loss partial,
// bit-identical arithmetic order. grid 1024 x 256.
// ---------------------------------------------------------------------------
__global__ __launch_bounds__(256)
void k_epi(const float* __restrict__ x, const float* __restrict__ cb,
           const int* __restrict__ best_idx, float* __restrict__ out1,
           float* __restrict__ enc, int* __restrict__ counts,
           double* __restrict__ partials) {
  const int t  = threadIdx.x;
  const int bh = blockIdx.x;
  const int b  = bh >> 6, h = bh & 63;
  __shared__ int idxs[64];
  if (t < 64) {
    const int myidx = best_idx[bh * 64 + t];
    idxs[t] = myidx;
    atomicAdd(counts + myidx, 1);
  }
  __syncthreads();

  {
    float* base = enc + (size_t)bh * 65536 + t * 4;
    #pragma unroll 8
    for (int r = 0; r < 64; ++r) {
      const int bi = idxs[r];
      f4u v = {0.f, 0.f, 0.f, 0.f};
      if ((bi >> 2) == t) {
        if ((bi & 3) == 0) v.x = 1.f; else if ((bi & 3) == 1) v.y = 1.f;
        else if ((bi & 3) == 2) v.z = 1.f; else v.w = 1.f;
      }
      __builtin_nontemporal_store(v, (f4u*)(base + r * 1024));
    }
  }

  const int w4 = (t & 15) * 4;
  const int cg = t >> 4;
  // preload q rows: qf[i][j] = cb[idxs[w4+i]][cg*16+j]  (identical values to
  // the old cb_t[c][idx] gathers; all-static indexing -> registers)
  float qf[4][16];
  #pragma unroll
  for (int i = 0; i < 4; ++i) {
    const float4* rp = (const float4*)(cb + idxs[w4 + i] * DIM + cg * 16);
    #pragma unroll
    for (int jq = 0; jq < 4; ++jq) {
      const float4 v = rp[jq];
      qf[i][jq * 4 + 0] = v.x; qf[i][jq * 4 + 1] = v.y;
      qf[i][jq * 4 + 2] = v.z; qf[i][jq * 4 + 3] = v.w;
    }
  }

  double s = 0.0;
  #pragma unroll
  for (int j = 0; j < 16; ++j) {
    const int c = cg * 16 + j;
    const size_t off = ((size_t)b << 20) + ((size_t)c << 12) + (h << 6) + w4;
    const float4 xp = *(const float4*)(x + off);
    const float q0 = qf[0][j], q1 = qf[1][j], q2 = qf[2][j], q3 = qf[3][j];
    const float d0 = __fsub_rn(q0, xp.x), d1 = __fsub_rn(q1, xp.y);
    const float d2 = __fsub_rn(q2, xp.z), d3 = __fsub_rn(q3, xp.w);
    f4u o;
    o.x = __fadd_rn(xp.x, d0); o.y = __fadd_rn(xp.y, d1);
    o.z = __fadd_rn(xp.z, d2); o.w = __fadd_rn(xp.w, d3);
    __builtin_nontemporal_store(o, (f4u*)(out1 + off));
    s += (double)(d0*d0) + (double)(d1*d1) + (double)(d2*d2) + (double)(d3*d3);
  }
  #pragma unroll
  for (int off = 32; off > 0; off >>= 1) s += __shfl_down(s, off);
  __shared__ double sm[4];
  if ((t & 63) == 0) sm[t >> 6] = s;
  __syncthreads();
  if (t == 0) partials[bh] = (sm[0] + sm[1]) + (sm[2] + sm[3]);
}

// ---------------------------------------------------------------------------
// k_final: loss + perplexity. grid 1 x 256
// ---------------------------------------------------------------------------
__global__ __launch_bounds__(256)
void k_final(const double* __restrict__ partials, const int* __restrict__ counts,
             float* __restrict__ out) {
  const int t = threadIdx.x;
  double s = 0.0;
  #pragma unroll
  for (int i = 0; i < 4; ++i) s += partials[t + i * 256];
  #pragma unroll
  for (int off = 32; off > 0; off >>= 1) s += __shfl_down(s, off);
  __shared__ double sm[4];
  __shared__ float smf[4];
  if ((t & 63) == 0) sm[t >> 6] = s;

  float ps = 0.f;
  #pragma unroll
  for (int i = 0; i < 4; ++i) {
    const float p = (float)counts[t + i * 256] * (1.0f / 65536.0f);
    ps += p * logf(1.0e10f + p);
  }
  #pragma unroll
  for (int off = 32; off > 0; off >>= 1) ps += __shfl_down(ps, off);
  if ((t & 63) == 0) smf[t >> 6] = ps;
  __syncthreads();
  if (t == 0) {
    const double tot = (sm[0] + sm[1]) + (sm[2] + sm[3]);
    const float mval = (float)(tot / 16777216.0);
    out[0] = mval + 0.25f * mval;
    out[PERP_OFF] = expf(-((smf[0] + smf[1]) + (smf[2] + smf[3])));
  }
}

// ---------------------------------------------------------------------------
extern "C" void kernel_launch(void* const* d_in, const int* in_sizes, int n_in,
                              void* d_out, int out_size, void* d_ws, size_t ws_size,
                              hipStream_t stream) {
  const float* x  = (const float*)d_in[0];   // (16,256,64,64) fp32
  const float* cb = (const float*)d_in[1];   // (1024,256) fp32
  float* out = (float*)d_out;
  char*  ws  = (char*)d_ws;

  int*            counts   = (int*)(ws + 0);                //   4 KB
  float*          cb_sq    = (float*)(ws + 4096);           //   4 KB
  int*            best_idx = (int*)(ws + 8192);             // 256 KB
  float*          in_sq    = (float*)(ws + 270336);         // 256 KB
  double*         partials = (double*)(ws + 532480);        //   8 KB
  unsigned short* e_bf16   = (unsigned short*)(ws + 1589248); // 512 KB
  unsigned int*   gcnt     = (unsigned int*)(ws + 2113536); // 256 KB
  unsigned short* glist    = (unsigned short*)(ws + 2375680); // 4 MB

  k_prep  <<<1024, 64, 0, stream>>>(cb, e_bf16, cb_sq, counts);
  k_score <<<SCORE_BLOCKS + 256, 256, 0, stream>>>(x, e_bf16, cb_sq, gcnt, glist, in_sq);
  k_refine<<<512, 256, 0, stream>>>(x, cb, cb_sq, in_sq, gcnt, glist, best_idx);
  k_epi   <<<1024, 256, 0, stream>>>(x, cb, best_idx, out + 1,
                                     out + ENC_OFF, counts, partials);
  k_final <<<1, 256, 0, stream>>>(partials, counts, out);
}

// Round 5
// 597.115 us; speedup vs baseline: 1.0914x; 1.0694x over previous
//
#include <hip/hip_runtime.h>
#include <math.h>
#include <stdint.h>

typedef float f4u __attribute__((ext_vector_type(4), aligned(4)));
typedef unsigned int u4v __attribute__((ext_vector_type(4)));
typedef __attribute__((ext_vector_type(8))) short short8;   // 8 bf16 (4 VGPR)
typedef __attribute__((ext_vector_type(4))) float float4v;  // MFMA acc

#define DIM 256
#define KCB 1024
#define PERP_OFF 16777217
#define ENC_OFF  16777218
#define CAP 32
#define EPS 0.008f
#define NPB 128            // n per score block
#define SCORE_BLOCKS 512   // 512 * 128 = 65536 n

// ---------------------------------------------------------------------------
// numpy pairwise sum-of-squares of a 128-block (8 accumulators, pairwise
// combine); squares rounded separately; no fma contraction.
// ---------------------------------------------------------------------------
__device__ __forceinline__ float np_sumsq128(const float* a, int stride) {
  float r[8];
  #pragma unroll
  for (int j = 0; j < 8; ++j) { float v = a[j * stride]; r[j] = __fmul_rn(v, v); }
  #pragma unroll
  for (int i = 8; i < 128; i += 8) {
    #pragma unroll
    for (int j = 0; j < 8; ++j) {
      float v = a[(i + j) * stride];
      r[j] = __fadd_rn(r[j], __fmul_rn(v, v));
    }
  }
  float s01 = __fadd_rn(r[0], r[1]);
  float s23 = __fadd_rn(r[2], r[3]);
  float s45 = __fadd_rn(r[4], r[5]);
  float s67 = __fadd_rn(r[6], r[7]);
  return __fadd_rn(__fadd_rn(s01, s23), __fadd_rn(s45, s67));
}

__device__ __forceinline__ unsigned short f2bf(float f) {
  unsigned u = __float_as_uint(f);
  u += 0x7FFFu + ((u >> 16) & 1u);     // RNE
  return (unsigned short)(u >> 16);
}

// ---------------------------------------------------------------------------
// k_prep: e_bf16[k][d], np-exact cb_sq[k], zero counts. grid 1024 x 64.
// ---------------------------------------------------------------------------
__global__ __launch_bounds__(64)
void k_prep(const float* __restrict__ cb, unsigned short* __restrict__ e_bf16,
            float* __restrict__ cb_sq, int* __restrict__ counts) {
  const int k = blockIdx.x;
  const int l = threadIdx.x;                  // 0..63
  float4 v = ((const float4*)(cb + k * DIM))[l];
  unsigned short bs[4] = {f2bf(v.x), f2bf(v.y), f2bf(v.z), f2bf(v.w)};
  *(ushort4*)(e_bf16 + k * DIM + l * 4) = *(ushort4*)bs;
  if (l == 0) {
    const float* p = cb + k * DIM;
    cb_sq[k] = __fadd_rn(np_sumsq128(p, 1), np_sumsq128(p + 128, 1));
    counts[k] = 0;
  }
}

// ---------------------------------------------------------------------------
// k_score v5 (SINGLE-PASS, score-only): bf16 MFMA approx scores
// s = cb_sq[k] - 2*dot. Online capture with running cross-lane min m;
// capture when s <= m + EPS (superset since m only decreases); end filter
// s <= m_final + EPS recovers EXACTLY the two-pass candidate set.
// insq role removed (moved into k_fused). grid 512 x 256.
//   A-frag: e_bf16[(ct*16 + l15)*256 + ks*32 + quad*8] (16B contiguous)
//   B-frag: gathered once from fp32 x (NCHW), packed bf16, held in VGPRs.
//   D: col=lane&15 = vector, row=quad*4+reg = code.  (layout HW-verified R4)
// ---------------------------------------------------------------------------
__global__ __launch_bounds__(256, 3)
void k_score(const float* __restrict__ x, const unsigned short* __restrict__ e_bf16,
             const float* __restrict__ cb_sq, unsigned int* __restrict__ gcnt,
             unsigned short* __restrict__ glist) {
  __shared__ unsigned int   lcnt[NPB];
  __shared__ unsigned short llist[NPB * CAP];   // 8KB
  __shared__ float          lsc[NPB * CAP];     // 16KB (captured approx scores)
  __shared__ float          lmin[NPB];          // per-n final min
  const int t    = threadIdx.x;
  const int wv   = t >> 6;
  const int lane = t & 63;
  const int l15  = lane & 15;
  const int quad = lane >> 4;
  if (t < NPB) lcnt[t] = 0;
  __syncthreads();

  // --- B-frag setup: 2 n-groups x 8 K-steps, gathered from fp32 x ---
  short8 Bf[2][8];
  const int nbase = blockIdx.x * NPB + wv * 32;
  #pragma unroll
  for (int g = 0; g < 2; ++g) {
    const int n = nbase + g * 16 + l15;
    const float* xb = x + (n >> 12) * 1048576 + (n & 4095);
    #pragma unroll
    for (int ks = 0; ks < 8; ++ks) {
      const int d0 = ks * 32 + quad * 8;
      union { unsigned short s[8]; short8 v; } u;
      #pragma unroll
      for (int j = 0; j < 8; ++j) u.s[j] = f2bf(xb[(d0 + j) * 4096]);
      Bf[g][ks] = u.v;
    }
  }

  // ---- single pass: MFMA + online min + online capture ----
  float m[2] = {1e30f, 1e30f};
  for (int ct = 0; ct < 64; ++ct) {
    float4v acc[2];
    #pragma unroll
    for (int g = 0; g < 2; ++g) acc[g] = (float4v){0.f, 0.f, 0.f, 0.f};
    const unsigned short* ap = e_bf16 + (ct * 16 + l15) * DIM + quad * 8;
    #pragma unroll
    for (int ks = 0; ks < 8; ++ks) {
      const short8 a = *(const short8*)(ap + ks * 32);
      #pragma unroll
      for (int g = 0; g < 2; ++g)
        acc[g] = __builtin_amdgcn_mfma_f32_16x16x32_bf16(a, Bf[g][ks], acc[g], 0, 0, 0);
    }
    const float4 cs = *(const float4*)(cb_sq + ct * 16 + quad * 4);
    #pragma unroll
    for (int g = 0; g < 2; ++g) {
      const float sa[4] = {fmaf(-2.f, acc[g].x, cs.x), fmaf(-2.f, acc[g].y, cs.y),
                           fmaf(-2.f, acc[g].z, cs.z), fmaf(-2.f, acc[g].w, cs.w)};
      // running cross-lane min for this n (fmin is exact -> order-independent)
      float bm = fminf(fminf(sa[0], sa[1]), fminf(sa[2], sa[3]));
      bm = fminf(bm, m[g]);
      bm = fminf(bm, __shfl_xor(bm, 16));
      bm = fminf(bm, __shfl_xor(bm, 32));
      m[g] = bm;
      const float thr = bm + EPS;
      const float sblk = fminf(fminf(sa[0], sa[1]), fminf(sa[2], sa[3]));
      if (sblk <= thr) {               // rare: skip whole capture block
        const int nl = wv * 32 + g * 16 + l15;
        #pragma unroll
        for (int r = 0; r < 4; ++r) {
          if (sa[r] <= thr) {
            unsigned slot = atomicAdd(&lcnt[nl], 1u);
            if (slot < CAP) {
              llist[nl * CAP + slot] = (unsigned short)(ct * 16 + quad * 4 + r);
              lsc[nl * CAP + slot]   = sa[r];
            }
          }
        }
      }
    }
  }
  // publish per-n final min (same value across quads after shfl reduction)
  if (quad == 0) {
    #pragma unroll
    for (int g = 0; g < 2; ++g) lmin[wv * 32 + g * 16 + l15] = m[g];
  }
  __syncthreads();

  // ---- filter to EXACT two-pass set: s <= m_final + EPS; compact in place,
  // then dump own row (no extra barrier: filter & dump same thread) ----
  if (t < NPB) {
    const unsigned cnt = lcnt[t];
    unsigned outc = cnt;
    if (cnt <= CAP) {
      const float thrf = lmin[t] + EPS;
      unsigned j = 0;
      for (unsigned i = 0; i < cnt; ++i) {
        const unsigned short c = llist[t * CAP + i];
        if (lsc[t * CAP + i] <= thrf) llist[t * CAP + j++] = c;
      }
      outc = j;
    }
    gcnt[blockIdx.x * NPB + t] = outc;

    // dump own row: CAP*2B = 64B = 4 x 16B
    u4v* gdst = (u4v*)(glist + (size_t)blockIdx.x * NPB * CAP);
    const u4v* lsrc = (const u4v*)llist;
    #pragma unroll
    for (int j = 0; j < 4; ++j)
      __builtin_nontemporal_store(lsrc[t * 4 + j], gdst + t * 4 + j);
  }
}

// ---------------------------------------------------------------------------
// k_fused: insq + refine + epilogue, one block per (b,h) tile (64 n, 64KB x).
// Phase 1: threads 0..63 compute np-exact in_sq (identical chain to old
//   k_insq) into LDS; pulls the x tile L1/L2-hot.
// Phase 2: refine, 4 threads/n. Per-candidate dist chains bit-identical to
//   old k_refine (same fmaf order, float4 cb reads); final pick is a pure
//   lexicographic min over (dist, idx) -> partition/order free; combine via
//   two shfl_xor. Overflow (cnt>CAP) -> exact full scan, repartitioned.
// Phase 3/4: old k_epi verbatim (enc one-hot nontemporal, xq + double loss),
//   x re-reads are cache-hot. grid 1024 x 256.
// ---------------------------------------------------------------------------
__global__ __launch_bounds__(256)
void k_fused(const float* __restrict__ x, const float* __restrict__ cb,
             const float* __restrict__ cb_sq,
             const unsigned int* __restrict__ gcnt,
             const unsigned short* __restrict__ glist,
             float* __restrict__ out1, float* __restrict__ enc,
             int* __restrict__ counts, double* __restrict__ partials) {
  const int t  = threadIdx.x;
  const int bh = blockIdx.x;
  const int b  = bh >> 6, h = bh & 63;
  __shared__ float isq_s[64];
  __shared__ int   idxs[64];

  // ---- phase 1: np-exact in_sq for this tile's 64 n (threads 0..63) ----
  if (t < 64) {
    const int n = bh * 64 + t;
    const float* p = x + b * 1048576 + (n & 4095);
    float h0 = np_sumsq128(p, 4096);
    float h1 = np_sumsq128(p + 128 * 4096, 4096);
    isq_s[t] = __fadd_rn(h0, h1);
  }
  __syncthreads();

  // ---- phase 2: refine, 4 threads per n ----
  {
    const int nl = t >> 2;            // 0..63
    const int q  = t & 3;
    const int n  = bh * 64 + nl;
    const unsigned cnt = gcnt[n];
    const float* xb = x + b * 1048576 + (n & 4095);
    const float isq = isq_s[nl];
    float bv = 1e30f; int bc = 0x7FFFFFFF;

    if (cnt <= CAP) {
      const unsigned short* lst = glist + (size_t)n * CAP;
      for (unsigned i = q; i < cnt; i += 4) {
        const int c1 = lst[i];
        const float4* e1 = (const float4*)(cb + c1 * DIM);
        float d1 = 0.f;
        #pragma unroll 4
        for (int qq = 0; qq < 64; ++qq) {
          const float4 a = e1[qq];
          d1 = fmaf(xb[(qq * 4 + 0) * 4096], a.x, d1);
          d1 = fmaf(xb[(qq * 4 + 1) * 4096], a.y, d1);
          d1 = fmaf(xb[(qq * 4 + 2) * 4096], a.z, d1);
          d1 = fmaf(xb[(qq * 4 + 3) * 4096], a.w, d1);
        }
        const float dist = __fsub_rn(__fadd_rn(isq, cb_sq[c1]), __fmul_rn(2.f, d1));
        if (dist < bv || (dist == bv && c1 < bc)) { bv = dist; bc = c1; }
      }
    } else {
      // overflow fallback (P ~ 1e-9): exact full scan
      for (int c = q; c < KCB; c += 4) {
        const float4* e1 = (const float4*)(cb + c * DIM);
        float d1 = 0.f;
        #pragma unroll 4
        for (int qq = 0; qq < 64; ++qq) {
          const float4 a = e1[qq];
          d1 = fmaf(xb[(qq * 4 + 0) * 4096], a.x, d1);
          d1 = fmaf(xb[(qq * 4 + 1) * 4096], a.y, d1);
          d1 = fmaf(xb[(qq * 4 + 2) * 4096], a.z, d1);
          d1 = fmaf(xb[(qq * 4 + 3) * 4096], a.w, d1);
        }
        const float dist = __fsub_rn(__fadd_rn(isq, cb_sq[c]), __fmul_rn(2.f, d1));
        if (dist < bv || (dist == bv && c < bc)) { bv = dist; bc = c; }
      }
    }
    // combine 4 lanes (lexmin -> order independent)
    {
      float ov = __shfl_xor(bv, 1); int oc = __shfl_xor(bc, 1);
      if (ov < bv || (ov == bv && oc < bc)) { bv = ov; bc = oc; }
      ov = __shfl_xor(bv, 2); oc = __shfl_xor(bc, 2);
      if (ov < bv || (ov == bv && oc < bc)) { bv = ov; bc = oc; }
    }
    if (q == 0) { idxs[nl] = bc; atomicAdd(counts + bc, 1); }
  }
  __syncthreads();

  // ---- phase 3: one-hot encodings (coalesced, nontemporal) ----
  {
    float* base = enc + (size_t)bh * 65536 + t * 4;
    #pragma unroll 8
    for (int r = 0; r < 64; ++r) {
      const int bi = idxs[r];
      f4u v = {0.f, 0.f, 0.f, 0.f};
      if ((bi >> 2) == t) {
        if ((bi & 3) == 0) v.x = 1.f; else if ((bi & 3) == 1) v.y = 1.f;
        else if ((bi & 3) == 2) v.z = 1.f; else v.w = 1.f;
      }
      __builtin_nontemporal_store(v, (f4u*)(base + r * 1024));
    }
  }

  // ---- phase 4: xq straight-through + double loss partial ----
  const int w4 = (t & 15) * 4;
  const int cg = t >> 4;
  float qf[4][16];
  #pragma unroll
  for (int i = 0; i < 4; ++i) {
    const float4* rp = (const float4*)(cb + idxs[w4 + i] * DIM + cg * 16);
    #pragma unroll
    for (int jq = 0; jq < 4; ++jq) {
      const float4 v = rp[jq];
      qf[i][jq * 4 + 0] = v.x; qf[i][jq * 4 + 1] = v.y;
      qf[i][jq * 4 + 2] = v.z; qf[i][jq * 4 + 3] = v.w;
    }
  }

  double s = 0.0;
  #pragma unroll
  for (int j = 0; j < 16; ++j) {
    const int c = cg * 16 + j;
    const size_t off = ((size_t)b << 20) + ((size_t)c << 12) + (h << 6) + w4;
    const float4 xp = *(const float4*)(x + off);
    const float q0 = qf[0][j], q1 = qf[1][j], q2 = qf[2][j], q3 = qf[3][j];
    const float d0 = __fsub_rn(q0, xp.x), d1 = __fsub_rn(q1, xp.y);
    const float d2 = __fsub_rn(q2, xp.z), d3 = __fsub_rn(q3, xp.w);
    f4u o;
    o.x = __fadd_rn(xp.x, d0); o.y = __fadd_rn(xp.y, d1);
    o.z = __fadd_rn(xp.z, d2); o.w = __fadd_rn(xp.w, d3);
    __builtin_nontemporal_store(o, (f4u*)(out1 + off));
    s += (double)(d0*d0) + (double)(d1*d1) + (double)(d2*d2) + (double)(d3*d3);
  }
  #pragma unroll
  for (int off = 32; off > 0; off >>= 1) s += __shfl_down(s, off);
  __shared__ double sm[4];
  if ((t & 63) == 0) sm[t >> 6] = s;
  __syncthreads();
  if (t == 0) partials[bh] = (sm[0] + sm[1]) + (sm[2] + sm[3]);
}

// ---------------------------------------------------------------------------
// k_final: loss + perplexity. grid 1 x 256
// ---------------------------------------------------------------------------
__global__ __launch_bounds__(256)
void k_final(const double* __restrict__ partials, const int* __restrict__ counts,
             float* __restrict__ out) {
  const int t = threadIdx.x;
  double s = 0.0;
  #pragma unroll
  for (int i = 0; i < 4; ++i) s += partials[t + i * 256];
  #pragma unroll
  for (int off = 32; off > 0; off >>= 1) s += __shfl_down(s, off);
  __shared__ double sm[4];
  __shared__ float smf[4];
  if ((t & 63) == 0) sm[t >> 6] = s;

  float ps = 0.f;
  #pragma unroll
  for (int i = 0; i < 4; ++i) {
    const float p = (float)counts[t + i * 256] * (1.0f / 65536.0f);
    ps += p * logf(1.0e10f + p);
  }
  #pragma unroll
  for (int off = 32; off > 0; off >>= 1) ps += __shfl_down(ps, off);
  if ((t & 63) == 0) smf[t >> 6] = ps;
  __syncthreads();
  if (t == 0) {
    const double tot = (sm[0] + sm[1]) + (sm[2] + sm[3]);
    const float mval = (float)(tot / 16777216.0);
    out[0] = mval + 0.25f * mval;
    out[PERP_OFF] = expf(-((smf[0] + smf[1]) + (smf[2] + smf[3])));
  }
}

// ---------------------------------------------------------------------------
extern "C" void kernel_launch(void* const* d_in, const int* in_sizes, int n_in,
                              void* d_out, int out_size, void* d_ws, size_t ws_size,
                              hipStream_t stream) {
  const float* x  = (const float*)d_in[0];   // (16,256,64,64) fp32
  const float* cb = (const float*)d_in[1];   // (1024,256) fp32
  float* out = (float*)d_out;
  char*  ws  = (char*)d_ws;

  int*            counts   = (int*)(ws + 0);                //   4 KB
  float*          cb_sq    = (float*)(ws + 4096);           //   4 KB
  double*         partials = (double*)(ws + 532480);        //   8 KB
  unsigned short* e_bf16   = (unsigned short*)(ws + 1589248); // 512 KB
  unsigned int*   gcnt     = (unsigned int*)(ws + 2113536); // 256 KB
  unsigned short* glist    = (unsigned short*)(ws + 2375680); // 4 MB

  k_prep  <<<1024, 64, 0, stream>>>(cb, e_bf16, cb_sq, counts);
  k_score <<<SCORE_BLOCKS, 256, 0, stream>>>(x, e_bf16, cb_sq, gcnt, glist);
  k_fused <<<1024, 256, 0, stream>>>(x, cb, cb_sq, gcnt, glist, out + 1,
                                     out + ENC_OFF, counts, partials);
  k_final <<<1, 256, 0, stream>>>(partials, counts, out);
}